// Round 1
// 3035.636 us; speedup vs baseline: 2.3578x; 2.3578x over previous
//
#include <hip/hip_runtime.h>
#include <stdint.h>
#include <math.h>

#define TSEQ   2048
#define DMODEL 768
#define NHEAD  12
#define HDIM   64
#define NLAYER 6
#define BATCH  2
#define NTOK   (BATCH*TSEQ)     // 4096
#define VOCAB  50257
#define VPAD   50304            // 393*128, padded for 128-wide N tiles
#define DFF    3072
#define QKVLD  2304             // q|k|v packed columns

typedef unsigned short ushort_t;
typedef short  bf16x8 __attribute__((ext_vector_type(8)));
typedef float  f32x4  __attribute__((ext_vector_type(4)));
typedef _Float16 f16;
typedef f16 f16x8 __attribute__((ext_vector_type(8)));
typedef f16 f16x2 __attribute__((ext_vector_type(2)));

// fp32 -> bf16 (RNE), bit-level so we don't depend on hip_bf16 API details
__device__ __forceinline__ ushort_t f2bf(float f) {
  unsigned u = __builtin_bit_cast(unsigned, f);
  u += 0x7fffu + ((u >> 16) & 1u);
  return (ushort_t)(u >> 16);
}

// fp32 -> fp16 bits
__device__ __forceinline__ ushort_t f2h(float f) {
  return __builtin_bit_cast(ushort_t, (f16)f);
}

// async global->LDS, 16B per lane; LDS dest = wave-uniform base + lane*16
typedef const __attribute__((address_space(1))) void* gas_ptr;
typedef __attribute__((address_space(3))) void*       las_ptr;
__device__ __forceinline__ void gl_lds16(const void* g, void* l) {
  __builtin_amdgcn_global_load_lds((gas_ptr)g, (las_ptr)l, 16, 0, 0);
}

// ---------------------------------------------------------------------------
// bf16 NT GEMM: C[M,N] = A[M,K] * B[N,K]^T, fp32 accum, fused epilogues.
// 128x128 tile, BK=32, 4 waves (2x2), 4x4 16x16x32 MFMA per wave. m97 pattern.
// EPI: 0 plain f32; 1 +res f32; 2 +bias,GELU -> bf16; 3 +bias,+res f32;
//      4 masked f32 store (lm_head, n < Nvalid, ld = Nvalid); 5 f16 store
// ---------------------------------------------------------------------------
template<int EPI>
__global__ __launch_bounds__(256, 2) void gemm_nt(
    const ushort_t* __restrict__ A, const ushort_t* __restrict__ B,
    int M, int N, int K,
    float* __restrict__ Of, ushort_t* __restrict__ Ob,
    const float* __restrict__ res, const float* __restrict__ bias,
    int ldO, int Nvalid)
{
  __shared__ ushort_t As[128 * 32];
  __shared__ ushort_t Bs[128 * 32];
  const int tid  = threadIdx.x;
  const int wave = tid >> 6, lane = tid & 63;
  const int wm = wave >> 1, wn = wave & 1;
  const long m0 = (long)blockIdx.y * 128;
  const long n0 = (long)blockIdx.x * 128;

  // staging chunks: 512 16B-chunks per tile, 2 per thread per matrix
  const int c0 = wave * 64 + lane;
  const int c1 = c0 + 256;
  const int ar0 = c0 >> 2, ak0 = (c0 & 3) * 8;
  const int ar1 = c1 >> 2, ak1 = (c1 & 3) * 8;
  const ushort_t* Ag0 = A + (m0 + ar0) * K + ak0;
  const ushort_t* Ag1 = A + (m0 + ar1) * K + ak1;
  const ushort_t* Bg0 = B + (n0 + ar0) * K + ak0;
  const ushort_t* Bg1 = B + (n0 + ar1) * K + ak1;
  ushort_t* AsW0 = As + (wave * 64) * 8;        // wave-uniform LDS bases
  ushort_t* AsW1 = As + (256 + wave * 64) * 8;
  ushort_t* BsW0 = Bs + (wave * 64) * 8;
  ushort_t* BsW1 = Bs + (256 + wave * 64) * 8;

  f32x4 acc[4][4];
  #pragma unroll
  for (int i = 0; i < 4; i++)
    #pragma unroll
    for (int j = 0; j < 4; j++) acc[i][j] = (f32x4){0.f, 0.f, 0.f, 0.f};

  const int lm = lane & 15, kq = (lane >> 4) * 8;
  const int mrow = wm * 64, nrow = wn * 64;

  for (int k0 = 0; k0 < K; k0 += 32) {
    gl_lds16(Ag0 + k0, AsW0);
    gl_lds16(Ag1 + k0, AsW1);
    gl_lds16(Bg0 + k0, BsW0);
    gl_lds16(Bg1 + k0, BsW1);
    __syncthreads();  // drains vmcnt (global_load_lds) before LDS reads
    bf16x8 a[4], b[4];
    #pragma unroll
    for (int i = 0; i < 4; i++)
      a[i] = *(const bf16x8*)(As + (mrow + i * 16 + lm) * 32 + kq);
    #pragma unroll
    for (int i = 0; i < 4; i++)
      b[i] = *(const bf16x8*)(Bs + (nrow + i * 16 + lm) * 32 + kq);
    #pragma unroll
    for (int mt = 0; mt < 4; mt++)
      #pragma unroll
      for (int nt = 0; nt < 4; nt++)
        acc[mt][nt] = __builtin_amdgcn_mfma_f32_16x16x32_bf16(
            a[mt], b[nt], acc[mt][nt], 0, 0, 0);
    __syncthreads();
  }

  // C/D frag: n = lane&15, m = (lane>>4)*4 + reg  [m89-verified mapping]
  const long mb = m0 + wm * 64;
  const long nb = n0 + wn * 64;
  #pragma unroll
  for (int mt = 0; mt < 4; mt++) {
    #pragma unroll
    for (int nt = 0; nt < 4; nt++) {
      const long n = nb + nt * 16 + lm;
      #pragma unroll
      for (int r = 0; r < 4; r++) {
        const long m = mb + mt * 16 + (lane >> 4) * 4 + r;
        float v = acc[mt][nt][r];
        if (EPI == 0) {
          Of[m * ldO + n] = v;
        } else if (EPI == 1) {
          Of[m * ldO + n] = v + res[m * ldO + n];
        } else if (EPI == 2) {
          v += bias[n];
          v = 0.5f * v * (1.0f + erff(v * 0.7071067811865475f));
          Ob[m * ldO + n] = f2bf(v);
        } else if (EPI == 3) {
          Of[m * ldO + n] = v + bias[n] + res[m * ldO + n];
        } else if (EPI == 4) {  // lm_head
          if (n < Nvalid) Of[m * (long)Nvalid + n] = v;
        } else {                // 5: f16 store (QKV for MFMA attention)
          Ob[m * ldO + n] = f2h(v);
        }
      }
    }
  }
}

// ---------------------------------------------------------------------------
// LayerNorm: one 256-thread block per row of 768, fp32 stats, bf16 out
// ---------------------------------------------------------------------------
__global__ __launch_bounds__(256) void ln_kernel(
    const float* __restrict__ x, const float* __restrict__ g,
    const float* __restrict__ b, ushort_t* __restrict__ out)
{
  const int row = blockIdx.x;
  const int tid = threadIdx.x;
  const float* xr = x + (long)row * DMODEL;
  const float v0 = xr[tid], v1 = xr[tid + 256], v2 = xr[tid + 512];
  float s = v0 + v1 + v2;
  float q = v0 * v0 + v1 * v1 + v2 * v2;
  #pragma unroll
  for (int o = 32; o; o >>= 1) {
    s += __shfl_xor(s, o, 64);
    q += __shfl_xor(q, o, 64);
  }
  __shared__ float red[8];
  const int wave = tid >> 6, lane = tid & 63;
  if (lane == 0) { red[wave] = s; red[wave + 4] = q; }
  __syncthreads();
  s = red[0] + red[1] + red[2] + red[3];
  q = red[4] + red[5] + red[6] + red[7];
  const float mu  = s * (1.0f / DMODEL);
  const float var = q * (1.0f / DMODEL) - mu * mu;
  const float rs  = rsqrtf(var + 1e-5f);
  ushort_t* orow = out + (long)row * DMODEL;
  orow[tid]       = f2bf((v0 - mu) * rs * g[tid]       + b[tid]);
  orow[tid + 256] = f2bf((v1 - mu) * rs * g[tid + 256] + b[tid + 256]);
  orow[tid + 512] = f2bf((v2 - mu) * rs * g[tid + 512] + b[tid + 512]);
}

// ---------------------------------------------------------------------------
// MFMA flash attention. One block = 64 query rows x one head x one batch.
// 4 waves; wave w owns q-rows [w*16, w*16+16). KV tiles of 64, causal.
// qkv is f16 [4096][2304]. S = Q.K^T and O += P.V via mfma_f32_16x16x32_f16,
// online softmax in fp32, all frags through LDS tiles padded to stride 72
// (144 B = 9*16 B: b128-aligned, row-walk lands on distinct bank quads).
// ---------------------------------------------------------------------------
__global__ __launch_bounds__(256) void attn_kernel(
    const ushort_t* __restrict__ qkvh, ushort_t* __restrict__ O)
{
  __shared__ ushort_t Qs[64 * 72];
  __shared__ ushort_t Ks[64 * 72];
  __shared__ ushort_t Vt[64 * 72];   // Vt[d][key]
  __shared__ ushort_t Ps[64 * 72];   // P[q][key] f16, wave-private 16-row strip
  const int tid  = threadIdx.x;
  const int wave = tid >> 6, lane = tid & 63;
  const int lm = lane & 15, lg = lane >> 4;
  const int qt = 31 - blockIdx.x;       // launch big (most-tiles) blocks first
  const int h  = blockIdx.y;
  const long rowbase = (long)blockIdx.z * TSEQ;
  const int t0  = qt * 64;
  const int wq0 = wave * 16;

  const f16* qk = (const f16*)qkvh;
  const long qbase = (rowbase + t0) * QKVLD + h * HDIM;

  // ---- stage Q tile (64x64 f16): 512 16B chunks, 2 per thread
  #pragma unroll
  for (int i = 0; i < 2; i++) {
    const int c = tid + i * 256;
    const int row = c >> 3, col8 = (c & 7) * 8;
    *(f16x8*)((f16*)Qs + row * 72 + col8) =
        *(const f16x8*)(qk + qbase + (long)row * QKVLD + col8);
  }
  __syncthreads();

  // hoist Q fragments (loop-invariant): A[m=q][k=d]
  f16x8 aQ[2];
  #pragma unroll
  for (int kk = 0; kk < 2; kk++)
    aQ[kk] = *(const f16x8*)((const f16*)Qs + (wq0 + lm) * 72 + kk * 32 + lg * 8);

  float mrun[4], lrun[4];
  f32x4 acco[4];
  #pragma unroll
  for (int r = 0; r < 4; r++) { mrun[r] = -1e30f; lrun[r] = 0.f; }
  #pragma unroll
  for (int dt = 0; dt < 4; dt++) acco[dt] = (f32x4){0.f, 0.f, 0.f, 0.f};

  for (int kt = 0; kt <= qt; kt++) {
    const long kbase = (rowbase + (long)kt * 64) * QKVLD + h * HDIM + DMODEL;
    // stage K tile row-major
    #pragma unroll
    for (int i = 0; i < 2; i++) {
      const int c = tid + i * 256;
      const int row = c >> 3, col8 = (c & 7) * 8;
      *(f16x8*)((f16*)Ks + row * 72 + col8) =
          *(const f16x8*)(qk + kbase + (long)row * QKVLD + col8);
    }
    // stage V transposed: thread loads keys {2kp,2kp+1} x 8 dims, writes f16x2
    {
      const int kp = tid & 31, d8 = (tid >> 5) * 8;
      const long vbase = kbase + DMODEL;
      const f16x8 v0 = *(const f16x8*)(qk + vbase + (long)(2 * kp)     * QKVLD + d8);
      const f16x8 v1 = *(const f16x8*)(qk + vbase + (long)(2 * kp + 1) * QKVLD + d8);
      #pragma unroll
      for (int j = 0; j < 8; j++) {
        f16x2 w; w[0] = v0[j]; w[1] = v1[j];
        *(f16x2*)((f16*)Vt + (d8 + j) * 72 + 2 * kp) = w;
      }
    }
    __syncthreads();

    // S = Q.K^T : D row m -> q = wq0+lg*4+r, col n -> key = nt*16+lm
    f32x4 accs[4];
    #pragma unroll
    for (int nt = 0; nt < 4; nt++) accs[nt] = (f32x4){0.f, 0.f, 0.f, 0.f};
    #pragma unroll
    for (int kk = 0; kk < 2; kk++) {
      #pragma unroll
      for (int nt = 0; nt < 4; nt++) {
        const f16x8 bK = *(const f16x8*)((const f16*)Ks + (nt * 16 + lm) * 72 + kk * 32 + lg * 8);
        accs[nt] = __builtin_amdgcn_mfma_f32_16x16x32_f16(aQ[kk], bK, accs[nt], 0, 0, 0);
      }
    }

    // causal mask only needed on the diagonal tile (kt==qt -> same 64-offset)
    if (kt == qt) {
      #pragma unroll
      for (int nt = 0; nt < 4; nt++)
        #pragma unroll
        for (int r = 0; r < 4; r++)
          if (nt * 16 + lm > wq0 + lg * 4 + r) accs[nt][r] = -1e30f;
    }

    // online softmax; scale 0.125 folded into exp arg (raw-max tracking)
    #pragma unroll
    for (int r = 0; r < 4; r++) {
      float mx = fmaxf(fmaxf(accs[0][r], accs[1][r]),
                       fmaxf(accs[2][r], accs[3][r]));
      #pragma unroll
      for (int o = 8; o; o >>= 1) mx = fmaxf(mx, __shfl_xor(mx, o, 64));
      const float mnew  = fmaxf(mrun[r], mx);
      const float alpha = __expf((mrun[r] - mnew) * 0.125f);
      mrun[r] = mnew;
      const float p0 = __expf((accs[0][r] - mnew) * 0.125f);
      const float p1 = __expf((accs[1][r] - mnew) * 0.125f);
      const float p2 = __expf((accs[2][r] - mnew) * 0.125f);
      const float p3 = __expf((accs[3][r] - mnew) * 0.125f);
      float psum = (p0 + p1) + (p2 + p3);
      #pragma unroll
      for (int o = 8; o; o >>= 1) psum += __shfl_xor(psum, o, 64);
      lrun[r] = lrun[r] * alpha + psum;
      #pragma unroll
      for (int dt = 0; dt < 4; dt++) acco[dt][r] *= alpha;
      f16* pr = (f16*)Ps + (wq0 + lg * 4 + r) * 72 + lm;
      pr[0]  = (f16)p0; pr[16] = (f16)p1; pr[32] = (f16)p2; pr[48] = (f16)p3;
    }
    // wave-private P strip: compiler fence so ds_writes precede ds_reads
    // (per-wave LDS ops complete in order; only compiler reordering is a risk)
    asm volatile("" ::: "memory");

    // O += P.V : A[m=q][k=key] from Ps, B[n=d][k=key] from Vt
    #pragma unroll
    for (int kk = 0; kk < 2; kk++) {
      const f16x8 aP = *(const f16x8*)((const f16*)Ps + (wq0 + lm) * 72 + kk * 32 + lg * 8);
      #pragma unroll
      for (int dt = 0; dt < 4; dt++) {
        const f16x8 bV = *(const f16x8*)((const f16*)Vt + (dt * 16 + lm) * 72 + kk * 32 + lg * 8);
        acco[dt] = __builtin_amdgcn_mfma_f32_16x16x32_f16(aP, bV, acco[dt], 0, 0, 0);
      }
    }
    __syncthreads();
  }

  float rinv[4];
  #pragma unroll
  for (int r = 0; r < 4; r++) rinv[r] = 1.0f / lrun[r];
  #pragma unroll
  for (int dt = 0; dt < 4; dt++) {
    #pragma unroll
    for (int r = 0; r < 4; r++) {
      const long trow = rowbase + t0 + wq0 + lg * 4 + r;
      O[trow * DMODEL + h * HDIM + dt * 16 + lm] = f2bf(acco[dt][r] * rinv[r]);
    }
  }
}

// ---------------------------------------------------------------------------
// elementwise helpers
// ---------------------------------------------------------------------------
__global__ __launch_bounds__(256) void embed_kernel(
    const int* __restrict__ idx, const float* __restrict__ wte,
    const float* __restrict__ wpe, float* __restrict__ x)
{
  const int i   = blockIdx.x * 256 + threadIdx.x;   // float4 id
  const int row = i / 192;
  const int c4  = (i % 192) * 4;
  const int t   = row & (TSEQ - 1);
  const int ix  = idx[row];
  const float4 a = *(const float4*)(wte + (long)ix * DMODEL + c4);
  const float4 p = *(const float4*)(wpe + (long)t * DMODEL + c4);
  float4 o;
  o.x = a.x + p.x; o.y = a.y + p.y; o.z = a.z + p.z; o.w = a.w + p.w;
  *(float4*)(x + (long)row * DMODEL + c4) = o;
}

__global__ __launch_bounds__(256) void cvtwte_kernel(
    const float* __restrict__ wte, ushort_t* __restrict__ wteb)
{
  const long i  = (long)blockIdx.x * 256 + threadIdx.x;  // float4 id
  const long n  = i / 192;
  const int  c4 = (int)(i % 192) * 4;
  ushort4 o;
  if (n < VOCAB) {
    const float4 v = *(const float4*)(wte + n * DMODEL + c4);
    o.x = f2bf(v.x); o.y = f2bf(v.y); o.z = f2bf(v.z); o.w = f2bf(v.w);
  } else {
    o.x = 0; o.y = 0; o.z = 0; o.w = 0;   // zero pad rows -> no effect on tiles
  }
  *(ushort4*)(wteb + n * DMODEL + c4) = o;
}

// transpose + fp32->bf16: src[R][C] f32 -> dst[C][R(ldd)] bf16
__global__ __launch_bounds__(256) void transp_kernel(
    const float* __restrict__ src, ushort_t* __restrict__ dst,
    int R, int C, int ldd)
{
  __shared__ float tl[32][33];
  const int tx = threadIdx.x, ty = threadIdx.y;
  const int r0 = blockIdx.y * 32, c0 = blockIdx.x * 32;
  #pragma unroll
  for (int i = 0; i < 4; i++)
    tl[ty + 8 * i][tx] = src[(long)(r0 + ty + 8 * i) * C + c0 + tx];
  __syncthreads();
  #pragma unroll
  for (int i = 0; i < 4; i++)
    dst[(long)(c0 + ty + 8 * i) * ldd + r0 + tx] = f2bf(tl[tx][ty + 8 * i]);
}

// ---------------------------------------------------------------------------
// workspace layout (bytes)
// ---------------------------------------------------------------------------
#define OFF_WTEB  0L                       // bf16 [50304][768]   77,266,944
#define OFF_X     77266944L                // f32  [4096][768]    12,582,912
#define OFF_HB    89849856L                // bf16 [4096][768]     6,291,456
#define OFF_QKV   96141312L                // f16  [4096][2304]   18,874,368 (region sized for f32, half used)
#define OFF_O     133890048L               // bf16 [4096][768]     6,291,456
#define OFF_MLPH  140181504L               // bf16 [4096][3072]   25,165,824
#define OFF_WQKVT 165347328L               // bf16 [2304][768]     3,538,944
#define OFF_WOT   168886272L               // bf16 [768][768]      1,179,648
#define OFF_W1T   170065920L               // bf16 [3072][768]     4,718,592
#define OFF_W2T   174784512L               // bf16 [768][3072]     4,718,592
// total: 179,503,104 bytes

extern "C" void kernel_launch(void* const* d_in, const int* in_sizes, int n_in,
                              void* d_out, int out_size, void* d_ws, size_t ws_size,
                              hipStream_t stream)
{
  const int*   idx  = (const int*)d_in[0];
  const float* wte  = (const float*)d_in[1];
  const float* wpe  = (const float*)d_in[2];
  const float* Wq   = (const float*)d_in[3];
  const float* Wk   = (const float*)d_in[4];
  const float* Wv   = (const float*)d_in[5];
  const float* Wo   = (const float*)d_in[6];
  const float* ln1g = (const float*)d_in[7];
  const float* ln1b = (const float*)d_in[8];
  const float* ln2g = (const float*)d_in[9];
  const float* ln2b = (const float*)d_in[10];
  const float* W1   = (const float*)d_in[11];
  const float* b1   = (const float*)d_in[12];
  const float* W2   = (const float*)d_in[13];
  const float* b2   = (const float*)d_in[14];
  const float* lnfg = (const float*)d_in[15];
  const float* lnfb = (const float*)d_in[16];
  float* out = (float*)d_out;

  char* ws = (char*)d_ws;
  ushort_t* wteb  = (ushort_t*)(ws + OFF_WTEB);
  float*    x     = (float*)(ws + OFF_X);
  ushort_t* hb    = (ushort_t*)(ws + OFF_HB);
  ushort_t* qkvh  = (ushort_t*)(ws + OFF_QKV);
  ushort_t* attO  = (ushort_t*)(ws + OFF_O);
  ushort_t* mlph  = (ushort_t*)(ws + OFF_MLPH);
  ushort_t* wqkvT = (ushort_t*)(ws + OFF_WQKVT);
  ushort_t* woT   = (ushort_t*)(ws + OFF_WOT);
  ushort_t* w1T   = (ushort_t*)(ws + OFF_W1T);
  ushort_t* w2T   = (ushort_t*)(ws + OFF_W2T);

  const dim3 tb(32, 8);

  cvtwte_kernel<<<37728, 256, 0, stream>>>(wte, wteb);      // VPAD*192/256
  embed_kernel<<<3072, 256, 0, stream>>>(idx, wte, wpe, x); // NTOK*192/256

  for (int l = 0; l < NLAYER; l++) {
    const float* wq = Wq + (long)l * DMODEL * DMODEL;
    const float* wk = Wk + (long)l * DMODEL * DMODEL;
    const float* wv = Wv + (long)l * DMODEL * DMODEL;
    const float* wo = Wo + (long)l * DMODEL * DMODEL;
    const float* w1 = W1 + (long)l * DMODEL * DFF;
    const float* w2 = W2 + (long)l * DFF * DMODEL;

    transp_kernel<<<dim3(24, 24), tb, 0, stream>>>(wq, wqkvT,              768, 768, 768);
    transp_kernel<<<dim3(24, 24), tb, 0, stream>>>(wk, wqkvT + 768 * 768,  768, 768, 768);
    transp_kernel<<<dim3(24, 24), tb, 0, stream>>>(wv, wqkvT + 1536 * 768, 768, 768, 768);
    transp_kernel<<<dim3(24, 24), tb, 0, stream>>>(wo, woT,                768, 768, 768);
    transp_kernel<<<dim3(96, 24), tb, 0, stream>>>(w1, w1T,                768, 3072, 768);
    transp_kernel<<<dim3(24, 96), tb, 0, stream>>>(w2, w2T,                3072, 768, 3072);

    ln_kernel<<<NTOK, 256, 0, stream>>>(x, ln1g + l * 768, ln1b + l * 768, hb);
    gemm_nt<5><<<dim3(18, 32), 256, 0, stream>>>(hb, wqkvT, NTOK, QKVLD, 768,
                                                 nullptr, qkvh, nullptr, nullptr, QKVLD, QKVLD);
    attn_kernel<<<dim3(32, NHEAD, BATCH), 256, 0, stream>>>(qkvh, attO);
    gemm_nt<1><<<dim3(6, 32), 256, 0, stream>>>(attO, woT, NTOK, 768, 768,
                                                x, nullptr, x, nullptr, 768, 768);
    ln_kernel<<<NTOK, 256, 0, stream>>>(x, ln2g + l * 768, ln2b + l * 768, hb);
    gemm_nt<2><<<dim3(24, 32), 256, 0, stream>>>(hb, w1T, NTOK, DFF, 768,
                                                 nullptr, mlph, nullptr, b1 + l * DFF, DFF, DFF);
    gemm_nt<3><<<dim3(6, 32), 256, 0, stream>>>(mlph, w2T, NTOK, 768, DFF,
                                                x, nullptr, x, b2 + l * 768, 768, 768);
  }

  ln_kernel<<<NTOK, 256, 0, stream>>>(x, lnfg, lnfb, hb);
  gemm_nt<4><<<dim3(VPAD / 128, 32), 256, 0, stream>>>(hb, wteb, NTOK, VPAD, 768,
                                                       out, nullptr, nullptr, nullptr,
                                                       VOCAB, VOCAB);
}